// Round 17
// baseline (1021.722 us; speedup 1.0000x reference)
//
#include <hip/hip_runtime.h>

#define LRC 0.01f
#define LSEQ 4096
#define HIDDIM 128

typedef float f32x2 __attribute__((ext_vector_type(2)));
typedef unsigned int u32x2 __attribute__((ext_vector_type(2)));

#define RL(x, L) __int_as_float(__builtin_amdgcn_readlane(__float_as_int(x), (L)))
#define RORADD(x, ctrl)                                                      \
  x += __int_as_float(__builtin_amdgcn_update_dpp(                           \
      0, __float_as_int(x), (ctrl), 0xf, 0xf, true))

// (validated R5..R14) 4 concurrent 64-lane sums, row-mapped outputs:
// row g holds sum of x_{sig(g)}, sig=[0,2,1,3]; rowlead write at
// sm[base+sig] lands value c at sm[base+c].
__device__ __forceinline__ float allred4(float x0, float x1, float x2,
                                         float x3) {
  u32x2 s1 = __builtin_amdgcn_permlane32_swap(__float_as_uint(x0),
                                              __float_as_uint(x1), false, false);
  float z01 = __uint_as_float(s1.x) + __uint_as_float(s1.y);
  u32x2 s2 = __builtin_amdgcn_permlane32_swap(__float_as_uint(x2),
                                              __float_as_uint(x3), false, false);
  float z23 = __uint_as_float(s2.x) + __uint_as_float(s2.y);
  u32x2 s3 = __builtin_amdgcn_permlane16_swap(__float_as_uint(z01),
                                              __float_as_uint(z23), false, false);
  float y = __uint_as_float(s3.x) + __uint_as_float(s3.y);
  RORADD(y, 0x128); RORADD(y, 0x124); RORADD(y, 0x122); RORADD(y, 0x121);
  return y;
}

// (validated R6/R13) 64-lane sum, all-lane-uniform result.
__device__ __forceinline__ float allred1(float x) {
  u32x2 s1 = __builtin_amdgcn_permlane32_swap(__float_as_uint(x),
                                              __float_as_uint(x), false, false);
  float z = __uint_as_float(s1.x) + __uint_as_float(s1.y);
  u32x2 s2 = __builtin_amdgcn_permlane16_swap(__float_as_uint(z),
                                              __float_as_uint(z), false, false);
  z = __uint_as_float(s2.x) + __uint_as_float(s2.y);
  RORADD(z, 0x128); RORADD(z, 0x124); RORADD(z, 0x122); RORADD(z, 0x121);
  return z;
}

__device__ __forceinline__ float dot2(f32x2 a, f32x2 b) {
  return fmaf(a.x, b.x, a.y * b.y);
}

// R13 (E=2, 533us) with s_barrier replaced by monotonic LDS flag sync.
// LDS floats: TP[ep][2][8] at ep*16 | KK[ep][5] at 32+ep*5 | DA[ep][2][8]
// at 48+ep*16. A@e: wait flagB>=e, read buf e&1, write DA e&1, post flagA=e.
// B@f: wait flagA>=f-1, read DA (f-1)&1, write TP/KK (f+1)&1, post flagB=f+1.
__global__ __launch_bounds__(128) void ttt_kernel(
    const float* __restrict__ h, const float* __restrict__ W1,
    const float* __restrict__ b1, const float* __restrict__ W2,
    const float* __restrict__ b2, float* __restrict__ out) {
  __shared__ __align__(16) float sm[80];
  __shared__ int flg[2];  // flg[0] = flagA, flg[1] = flagB
  volatile int* vf = flg;
  const int bq = blockIdx.x;
  const int tid = threadIdx.x;
  const int wv = tid >> 6;
  const int lane = tid & 63;
  const int g = lane >> 4;
  const int sig = ((g & 1) << 1) | (g >> 1);
  const int d0 = lane * 2;
  const bool rowlead = ((lane & 15) == 0);
  const float* __restrict__ hb = h + (size_t)bq * (LSEQ * HIDDIM);

  if (tid == 0) {
    flg[0] = -1;
    flg[1] = -1;
  }
  __syncthreads();  // one real barrier: flag init visible to both waves

  if (wv == 0) {
    // ======================= WAVE A (serial core) =======================
    const float cneg = -(LRC * 2.0f / (float)HIDDIM);
    f32x2 w2v[8];
#pragma unroll
    for (int i = 0; i < 8; ++i) {
      w2v[i].x = W2[(size_t)d0 * 8 + i];
      w2v[i].y = W2[(size_t)(d0 + 1) * 8 + i];
    }
    f32x2 b2v = *(const f32x2*)(b2 + d0);
    float b1A = b1[sig], b1B = b1[4 + sig];
    // v(j) = row 2j+1; 4 live slots (2 epochs)
    f32x2 vS[4];
#pragma unroll
    for (int x = 0; x < 4; ++x)
      vS[x] = *(const f32x2*)(hb + (size_t)(2 * x + 1) * HIDDIM + d0);
    float pGlx = 0.0f, pGly = 0.0f;
    float pR0 = 0, pR1 = 0, pR2 = 0, pR3 = 0, pR4 = 0, pR5 = 0, pR6 = 0,
          pR7 = 0;
    float dm2A = 0, dm2B = 0, dm1A = 0, dm1B = 0;

    auto CORE = [&](float aA, float aB, f32x2 vcur, float& daAo, float& daBo,
                    bool defer) {
      float rA = fmaxf(aA, 0.0f), rB = fmaxf(aB, 0.0f);
      float r0 = RL(rA, 0), r1 = RL(rA, 32), r2 = RL(rA, 16), r3 = RL(rA, 48);
      float r4 = RL(rB, 0), r5 = RL(rB, 32), r6 = RL(rB, 16), r7 = RL(rB, 48);
      float px0 = fmaf(w2v[0].x, r0, b2v.x), py0 = fmaf(w2v[0].y, r0, b2v.y);
      float px1 = w2v[1].x * r1, py1 = w2v[1].y * r1;
      px0 = fmaf(w2v[2].x, r2, px0); py0 = fmaf(w2v[2].y, r2, py0);
      px1 = fmaf(w2v[3].x, r3, px1); py1 = fmaf(w2v[3].y, r3, py1);
      px0 = fmaf(w2v[4].x, r4, px0); py0 = fmaf(w2v[4].y, r4, py0);
      px1 = fmaf(w2v[5].x, r5, px1); py1 = fmaf(w2v[5].y, r5, py1);
      px0 = fmaf(w2v[6].x, r6, px0); py0 = fmaf(w2v[6].y, r6, py0);
      px1 = fmaf(w2v[7].x, r7, px1); py1 = fmaf(w2v[7].y, r7, py1);
      float glx = (px0 + px1 - vcur.x) * cneg;
      float gly = (py0 + py1 - vcur.y) * cneg;
      float dp[8];
#pragma unroll
      for (int i = 0; i < 8; ++i) dp[i] = fmaf(w2v[i].x, glx, w2v[i].y * gly);
      float zA = allred4(dp[0], dp[1], dp[2], dp[3]);
      float zB = allred4(dp[4], dp[5], dp[6], dp[7]);
      daAo = (aA > 0.0f) ? zA : 0.0f;  // == -lr * da_ref
      daBo = (aB > 0.0f) ? zB : 0.0f;
      if (!defer) {
        w2v[0].x = fmaf(glx, r0, w2v[0].x); w2v[0].y = fmaf(gly, r0, w2v[0].y);
        w2v[1].x = fmaf(glx, r1, w2v[1].x); w2v[1].y = fmaf(gly, r1, w2v[1].y);
        w2v[2].x = fmaf(glx, r2, w2v[2].x); w2v[2].y = fmaf(gly, r2, w2v[2].y);
        w2v[3].x = fmaf(glx, r3, w2v[3].x); w2v[3].y = fmaf(gly, r3, w2v[3].y);
        w2v[4].x = fmaf(glx, r4, w2v[4].x); w2v[4].y = fmaf(gly, r4, w2v[4].y);
        w2v[5].x = fmaf(glx, r5, w2v[5].x); w2v[5].y = fmaf(gly, r5, w2v[5].y);
        w2v[6].x = fmaf(glx, r6, w2v[6].x); w2v[6].y = fmaf(gly, r6, w2v[6].y);
        w2v[7].x = fmaf(glx, r7, w2v[7].x); w2v[7].y = fmaf(gly, r7, w2v[7].y);
        b2v.x += glx;
        b2v.y += gly;
      } else {
        pGlx = glx; pGly = gly;
        pR0 = r0; pR1 = r1; pR2 = r2; pR3 = r3;
        pR4 = r4; pR5 = r5; pR6 = r6; pR7 = r7;
      }
    };
    auto APPLY_PEND = [&]() {
      w2v[0].x = fmaf(pGlx, pR0, w2v[0].x); w2v[0].y = fmaf(pGly, pR0, w2v[0].y);
      w2v[1].x = fmaf(pGlx, pR1, w2v[1].x); w2v[1].y = fmaf(pGly, pR1, w2v[1].y);
      w2v[2].x = fmaf(pGlx, pR2, w2v[2].x); w2v[2].y = fmaf(pGly, pR2, w2v[2].y);
      w2v[3].x = fmaf(pGlx, pR3, w2v[3].x); w2v[3].y = fmaf(pGly, pR3, w2v[3].y);
      w2v[4].x = fmaf(pGlx, pR4, w2v[4].x); w2v[4].y = fmaf(pGly, pR4, w2v[4].y);
      w2v[5].x = fmaf(pGlx, pR5, w2v[5].x); w2v[5].y = fmaf(pGly, pR5, w2v[5].y);
      w2v[6].x = fmaf(pGlx, pR6, w2v[6].x); w2v[6].y = fmaf(pGly, pR6, w2v[6].y);
      w2v[7].x = fmaf(pGlx, pR7, w2v[7].x); w2v[7].y = fmaf(pGly, pR7, w2v[7].y);
      b2v.x += pGlx;
      b2v.y += pGly;
    };

    auto EPA = [&](int e) {
      const int ep = e & 1;
      const int tpo = ep * 16, kko = 32 + ep * 5, dao = 48 + ep * 16;
      // v prefetch for epoch e+2 (issue before the spin; stays in flight)
      int rv0 = 4 * e + 9;  if (rv0 > 4095) rv0 = 4095;
      int rv1 = 4 * e + 11; if (rv1 > 4095) rv1 = 4095;
      f32x2 vI0 = *(const f32x2*)(hb + (size_t)rv0 * HIDDIM + d0);
      f32x2 vI1 = *(const f32x2*)(hb + (size_t)rv1 * HIDDIM + d0);
      // wait for B's buffer e
      while (vf[1] < e) {}
      asm volatile("" ::: "memory");
      float tpPA = sm[tpo + sig], tpPB = sm[tpo + 4 + sig];
      float tpQA = sm[tpo + 8 + sig], tpQB = sm[tpo + 12 + sig];
      float kk1 = sm[kko], kk2 = sm[kko + 1], kk3 = sm[kko + 2],
            kk4 = sm[kko + 3], kk5 = sm[kko + 4];
      APPLY_PEND();  // prev epoch's deferred W2/b2; shadows the LDS reads
      float aA = fmaf(dm2A, kk1, fmaf(dm1A, kk2, tpPA + b1A));
      float aB = fmaf(dm2B, kk1, fmaf(dm1B, kk2, tpPB + b1B));
      float daPA, daPB;
      CORE(aA, aB, vS[0], daPA, daPB, false);
      if (rowlead) { sm[dao + sig] = daPA; sm[dao + 4 + sig] = daPB; }
      b1A += daPA;
      b1B += daPB;
      float aQA = fmaf(dm2A, kk3, fmaf(dm1A, kk4, fmaf(daPA, kk5, tpQA + b1A)));
      float aQB = fmaf(dm2B, kk3, fmaf(dm1B, kk4, fmaf(daPB, kk5, tpQB + b1B)));
      float daQA, daQB;
      CORE(aQA, aQB, vS[1], daQA, daQB, true);
      if (rowlead) { sm[dao + 8 + sig] = daQA; sm[dao + 12 + sig] = daQB; }
      b1A += daQA;
      b1B += daQB;
      dm2A = daPA; dm2B = daPB;
      dm1A = daQA; dm1B = daQB;
      vS[0] = vS[2]; vS[1] = vS[3]; vS[2] = vI0; vS[3] = vI1;
      // publish DA(e)
      asm volatile("s_waitcnt lgkmcnt(0)" ::: "memory");
      if (lane == 0) vf[0] = e;
    };

    for (int e = 0; e < 1023; ++e) EPA(e);
    // ---- tail epoch 1023 (buffer 1): step 2046 + final predict ----
    {
      while (vf[1] < 1023) {}
      asm volatile("" ::: "memory");
      float tpPA = sm[16 + sig], tpPB = sm[20 + sig];
      float tpQA = sm[24 + sig], tpQB = sm[28 + sig];
      float kk1 = sm[37], kk2 = sm[38], kk3 = sm[39], kk4 = sm[40],
            kk5 = sm[41];
      APPLY_PEND();
      float aA = fmaf(dm2A, kk1, fmaf(dm1A, kk2, tpPA + b1A));
      float aB = fmaf(dm2B, kk1, fmaf(dm1B, kk2, tpPB + b1B));
      float daA, daB;
      CORE(aA, aB, vS[0], daA, daB, false);  // step 2046
      b1A += daA;
      b1B += daB;
      // a(2047) = W1_fin·x + b1_fin  (x fed through as k(2047))
      float fA = fmaf(dm2A, kk3, fmaf(dm1A, kk4, fmaf(daA, kk5, tpQA + b1A)));
      float fB = fmaf(dm2B, kk3, fmaf(dm1B, kk4, fmaf(daB, kk5, tpQB + b1B)));
      float rA = fmaxf(fA, 0.0f), rB = fmaxf(fB, 0.0f);
      float r0 = RL(rA, 0), r1 = RL(rA, 32), r2 = RL(rA, 16), r3 = RL(rA, 48);
      float r4 = RL(rB, 0), r5 = RL(rB, 32), r6 = RL(rB, 16), r7 = RL(rB, 48);
      float ox = fmaf(w2v[0].x, r0, b2v.x), oy = fmaf(w2v[0].y, r0, b2v.y);
      ox = fmaf(w2v[1].x, r1, ox); oy = fmaf(w2v[1].y, r1, oy);
      ox = fmaf(w2v[2].x, r2, ox); oy = fmaf(w2v[2].y, r2, oy);
      ox = fmaf(w2v[3].x, r3, ox); oy = fmaf(w2v[3].y, r3, oy);
      ox = fmaf(w2v[4].x, r4, ox); oy = fmaf(w2v[4].y, r4, oy);
      ox = fmaf(w2v[5].x, r5, ox); oy = fmaf(w2v[5].y, r5, oy);
      ox = fmaf(w2v[6].x, r6, ox); oy = fmaf(w2v[6].y, r6, oy);
      ox = fmaf(w2v[7].x, r7, ox); oy = fmaf(w2v[7].y, r7, oy);
      f32x2 o = {ox, oy};
      *(f32x2*)(out + (size_t)bq * HIDDIM + d0) = o;
    }
  } else {
    // ======================= WAVE B (W1 owner) =======================
    f32x2 w1v[8];
#pragma unroll
    for (int i = 0; i < 8; ++i)
      w1v[i] = *(const f32x2*)(W1 + i * HIDDIM + d0);
    // k(m) = row 2m (m<2047); k(2047) := x = row 4095
    f32x2 kR2 = *(const f32x2*)(hb + 0 * HIDDIM + d0);   // k(0)
    f32x2 kR3 = *(const f32x2*)(hb + 2 * HIDDIM + d0);   // k(1)
    f32x2 kR4 = *(const f32x2*)(hb + 4 * HIDDIM + d0);   // k(2)
    f32x2 kR5 = *(const f32x2*)(hb + 6 * HIDDIM + d0);   // k(3)
    f32x2 kR0 = kR2, kR1 = kR2;                          // dummies (da=0)
    f32x2 kI0 = *(const f32x2*)(hb + 8 * HIDDIM + d0);   // k(4)
    f32x2 kI1 = *(const f32x2*)(hb + 10 * HIDDIM + d0);  // k(5)
    // zero DA[1] (read at f=1 wait... actually at f=0+1 parity; A overwrites
    // before any real use, but epoch-0 B read needs defined zeros)
    if (lane < 16) sm[64 + lane] = 0.0f;
    // init buffer 0: a(0) base, TP(1), kk
    {
      float pa[8], pb[8];
#pragma unroll
      for (int i = 0; i < 8; ++i) {
        pa[i] = dot2(w1v[i], kR2);
        pb[i] = dot2(w1v[i], kR3);
      }
      float zA = allred4(pa[0], pa[1], pa[2], pa[3]);
      float zB = allred4(pa[4], pa[5], pa[6], pa[7]);
      float tA = allred4(pb[0], pb[1], pb[2], pb[3]);
      float tB = allred4(pb[4], pb[5], pb[6], pb[7]);
      float kk01 = allred1(dot2(kR2, kR3));
      if (rowlead) {
        sm[0 + sig] = zA;   sm[4 + sig] = zB;
        sm[8 + sig] = tA;   sm[12 + sig] = tB;
      }
      if (lane < 4) sm[32 + lane] = 0.0f;  // kk1..kk4 = 0 (da=0 at epoch 0)
      if (lane == 0) sm[36] = kk01;        // kk5 = k(0)·k(1)
    }
    asm volatile("s_waitcnt lgkmcnt(0)" ::: "memory");
    if (lane == 0) vf[1] = 0;  // buffer for epoch 0 ready

    auto EPB = [&](int f) {
      const int ep = f & 1;
      const int dao = 48 + (1 - ep) * 16;
      const int tpo = (1 - ep) * 16, kko = 32 + (1 - ep) * 5;
      // k prefetch (issue before the spin; stays in flight)
      int m6 = 2 * f + 6, m7 = 2 * f + 7;
      int r6 = (m6 >= 2047) ? 4095 : 2 * m6;
      int r7 = (m7 >= 2047) ? 4095 : 2 * m7;
      f32x2 kN0 = *(const f32x2*)(hb + (size_t)r6 * HIDDIM + d0);
      f32x2 kN1 = *(const f32x2*)(hb + (size_t)r7 * HIDDIM + d0);
      // kk partials + reduces (k-only; independent of DA)
      float c1 = dot2(kR2, kR4), c2 = dot2(kR3, kR4);
      float c3 = dot2(kR2, kR5), c4 = dot2(kR3, kR5);
      float c5 = dot2(kR4, kR5);
      float ykk = allred4(c1, c2, c3, c4);
      float yk5 = allred1(c5);
      // wait for A's DA(f-1)
      while (vf[0] < f - 1) {}
      asm volatile("" ::: "memory");
      float4 q0 = *(float4*)&sm[dao], q1 = *(float4*)&sm[dao + 4];
      float4 q2 = *(float4*)&sm[dao + 8], q3 = *(float4*)&sm[dao + 12];
      if (rowlead) sm[kko + sig] = ykk;
      if (lane == 0) sm[kko + 4] = yk5;
      float dP[8] = {q0.x, q0.y, q0.z, q0.w, q1.x, q1.y, q1.z, q1.w};
      float dQ[8] = {q2.x, q2.y, q2.z, q2.w, q3.x, q3.y, q3.z, q3.w};
#pragma unroll
      for (int i = 0; i < 8; ++i) {
        w1v[i].x = fmaf(dP[i], kR0.x, w1v[i].x);
        w1v[i].y = fmaf(dP[i], kR0.y, w1v[i].y);
        w1v[i].x = fmaf(dQ[i], kR1.x, w1v[i].x);
        w1v[i].y = fmaf(dQ[i], kR1.y, w1v[i].y);
      }
      float tp[8];
#pragma unroll
      for (int i = 0; i < 8; ++i) tp[i] = dot2(w1v[i], kR4);
      float tA = allred4(tp[0], tp[1], tp[2], tp[3]);
      float tB = allred4(tp[4], tp[5], tp[6], tp[7]);
#pragma unroll
      for (int i = 0; i < 8; ++i) tp[i] = dot2(w1v[i], kR5);
      float uA = allred4(tp[0], tp[1], tp[2], tp[3]);
      float uB = allred4(tp[4], tp[5], tp[6], tp[7]);
      if (rowlead) {
        sm[tpo + sig] = tA;      sm[tpo + 4 + sig] = tB;
        sm[tpo + 8 + sig] = uA;  sm[tpo + 12 + sig] = uB;
      }
      kR0 = kR2; kR1 = kR3; kR2 = kR4; kR3 = kR5;
      kR4 = kI0; kR5 = kI1; kI0 = kN0; kI1 = kN1;
      // publish buffer f+1
      asm volatile("s_waitcnt lgkmcnt(0)" ::: "memory");
      if (lane == 0) vf[1] = f + 1;
    };

    for (int f = 0; f < 1023; ++f) EPB(f);
  }
}

extern "C" void kernel_launch(void* const* d_in, const int* in_sizes, int n_in,
                              void* d_out, int out_size, void* d_ws, size_t ws_size,
                              hipStream_t stream) {
  const float* h  = (const float*)d_in[0];
  const float* W1 = (const float*)d_in[1];
  const float* b1 = (const float*)d_in[2];
  const float* W2 = (const float*)d_in[3];
  const float* b2 = (const float*)d_in[4];
  float* out = (float*)d_out;
  ttt_kernel<<<256, 128, 0, stream>>>(h, W1, b1, W2, b2, out);
}

// Round 18
// 605.672 us; speedup vs baseline: 1.6869x; 1.6869x over previous
//
#include <hip/hip_runtime.h>

#define LRC 0.01f
#define LSEQ 4096
#define HIDDIM 128

typedef float f32x2 __attribute__((ext_vector_type(2)));
typedef unsigned int u32x2 __attribute__((ext_vector_type(2)));

#define RL(x, L) __int_as_float(__builtin_amdgcn_readlane(__float_as_int(x), (L)))
#define PKFMA(a, b, c) __builtin_elementwise_fma((a), (b), (c))
#define RORADD(x, ctrl)                                                      \
  x += __int_as_float(__builtin_amdgcn_update_dpp(                           \
      0, __float_as_int(x), (ctrl), 0xf, 0xf, true))

// (validated R5..R14) 4 concurrent 64-lane sums, row-mapped outputs:
// row g holds sum of x_{sig(g)}, sig=[0,2,1,3]; rowlead write at
// sm[base+sig] lands value c at sm[base+c].
__device__ __forceinline__ float allred4(float x0, float x1, float x2,
                                         float x3) {
  u32x2 s1 = __builtin_amdgcn_permlane32_swap(__float_as_uint(x0),
                                              __float_as_uint(x1), false, false);
  float z01 = __uint_as_float(s1.x) + __uint_as_float(s1.y);
  u32x2 s2 = __builtin_amdgcn_permlane32_swap(__float_as_uint(x2),
                                              __float_as_uint(x3), false, false);
  float z23 = __uint_as_float(s2.x) + __uint_as_float(s2.y);
  u32x2 s3 = __builtin_amdgcn_permlane16_swap(__float_as_uint(z01),
                                              __float_as_uint(z23), false, false);
  float y = __uint_as_float(s3.x) + __uint_as_float(s3.y);
  RORADD(y, 0x128); RORADD(y, 0x124); RORADD(y, 0x122); RORADD(y, 0x121);
  return y;
}

// (validated R6/R13) 64-lane sum, all-lane-uniform result.
__device__ __forceinline__ float allred1(float x) {
  u32x2 s1 = __builtin_amdgcn_permlane32_swap(__float_as_uint(x),
                                              __float_as_uint(x), false, false);
  float z = __uint_as_float(s1.x) + __uint_as_float(s1.y);
  u32x2 s2 = __builtin_amdgcn_permlane16_swap(__float_as_uint(z),
                                              __float_as_uint(z), false, false);
  z = __uint_as_float(s2.x) + __uint_as_float(s2.y);
  RORADD(z, 0x128); RORADD(z, 0x124); RORADD(z, 0x122); RORADD(z, 0x121);
  return z;
}

// Barrier WITHOUT vmcnt drain: global prefetches stay in flight.
#define BAR() asm volatile("s_waitcnt lgkmcnt(0)\n\ts_barrier" ::: "memory")

__device__ __forceinline__ float dot2(f32x2 a, f32x2 b) {
  return fmaf(a.x, b.x, a.y * b.y);
}
static __device__ __forceinline__ f32x2 splat2(float s) {
  f32x2 r; r.x = s; r.y = s; return r;
}

// R13 (E=2, 533us) + packed-f32 math on all d-distributed blocks.
// LDS floats: TP[ep][2][8] at ep*16 | KK[ep][5] at 32+ep*5 | DA[ep][2][8]
// at 48+ep*16. A@e: reads TP/KK[e&1] (B wrote in e-1), writes DA[e&1];
// B@f: reads DA[(f-1)&1], writes TP/KK[(f+1)&1]. One barrier per epoch.
__global__ __launch_bounds__(128) void ttt_kernel(
    const float* __restrict__ h, const float* __restrict__ W1,
    const float* __restrict__ b1, const float* __restrict__ W2,
    const float* __restrict__ b2, float* __restrict__ out) {
  __shared__ __align__(16) float sm[80];
  const int b = blockIdx.x;
  const int tid = threadIdx.x;
  const int wv = tid >> 6;
  const int lane = tid & 63;
  const int g = lane >> 4;
  const int sig = ((g & 1) << 1) | (g >> 1);
  const int d0 = lane * 2;
  const bool rowlead = ((lane & 15) == 0);
  const float* __restrict__ hb = h + (size_t)b * (LSEQ * HIDDIM);

  if (wv == 0) {
    // ======================= WAVE A (serial core) =======================
    const float cneg = -(LRC * 2.0f / (float)HIDDIM);
    const f32x2 cnegv = {cneg, cneg};
    f32x2 w2v[8];
#pragma unroll
    for (int i = 0; i < 8; ++i) {
      w2v[i].x = W2[(size_t)d0 * 8 + i];
      w2v[i].y = W2[(size_t)(d0 + 1) * 8 + i];
    }
    f32x2 b2v = *(const f32x2*)(b2 + d0);
    float b1A = b1[sig], b1B = b1[4 + sig];
    // v(j) = row 2j+1; 4 live slots (2 epochs)
    f32x2 vS[4];
#pragma unroll
    for (int x = 0; x < 4; ++x)
      vS[x] = *(const f32x2*)(hb + (size_t)(2 * x + 1) * HIDDIM + d0);
    f32x2 pGl = {0.0f, 0.0f};
    float pR0 = 0, pR1 = 0, pR2 = 0, pR3 = 0, pR4 = 0, pR5 = 0, pR6 = 0,
          pR7 = 0;
    float dm2A = 0, dm2B = 0, dm1A = 0, dm1B = 0;

    auto CORE = [&](float aA, float aB, f32x2 vcur, float& daAo, float& daBo,
                    bool defer) {
      float rA = fmaxf(aA, 0.0f), rB = fmaxf(aB, 0.0f);
      float r0 = RL(rA, 0), r1 = RL(rA, 32), r2 = RL(rA, 16), r3 = RL(rA, 48);
      float r4 = RL(rB, 0), r5 = RL(rB, 32), r6 = RL(rB, 16), r7 = RL(rB, 48);
      f32x2 rr0 = splat2(r0), rr1 = splat2(r1), rr2 = splat2(r2),
            rr3 = splat2(r3), rr4 = splat2(r4), rr5 = splat2(r5),
            rr6 = splat2(r6), rr7 = splat2(r7);
      // pred = W2 r + b2 (packed, two partial accumulators)
      f32x2 p0 = PKFMA(w2v[0], rr0, b2v);
      f32x2 p1 = w2v[1] * rr1;
      p0 = PKFMA(w2v[2], rr2, p0);
      p1 = PKFMA(w2v[3], rr3, p1);
      p0 = PKFMA(w2v[4], rr4, p0);
      p1 = PKFMA(w2v[5], rr5, p1);
      p0 = PKFMA(w2v[6], rr6, p0);
      p1 = PKFMA(w2v[7], rr7, p1);
      f32x2 gl = ((p0 + p1) - vcur) * cnegv;
      // dp partials on OLD w2 (horizontal; stays scalar)
      float dp[8];
#pragma unroll
      for (int i = 0; i < 8; ++i) dp[i] = fmaf(w2v[i].x, gl.x, w2v[i].y * gl.y);
      float zA = allred4(dp[0], dp[1], dp[2], dp[3]);
      float zB = allred4(dp[4], dp[5], dp[6], dp[7]);
      daAo = (aA > 0.0f) ? zA : 0.0f;  // == -lr * da_ref
      daBo = (aB > 0.0f) ? zB : 0.0f;
      if (!defer) {
        w2v[0] = PKFMA(gl, rr0, w2v[0]);
        w2v[1] = PKFMA(gl, rr1, w2v[1]);
        w2v[2] = PKFMA(gl, rr2, w2v[2]);
        w2v[3] = PKFMA(gl, rr3, w2v[3]);
        w2v[4] = PKFMA(gl, rr4, w2v[4]);
        w2v[5] = PKFMA(gl, rr5, w2v[5]);
        w2v[6] = PKFMA(gl, rr6, w2v[6]);
        w2v[7] = PKFMA(gl, rr7, w2v[7]);
        b2v += gl;
      } else {
        pGl = gl;
        pR0 = r0; pR1 = r1; pR2 = r2; pR3 = r3;
        pR4 = r4; pR5 = r5; pR6 = r6; pR7 = r7;
      }
    };
    auto APPLY_PEND = [&]() {
      w2v[0] = PKFMA(pGl, splat2(pR0), w2v[0]);
      w2v[1] = PKFMA(pGl, splat2(pR1), w2v[1]);
      w2v[2] = PKFMA(pGl, splat2(pR2), w2v[2]);
      w2v[3] = PKFMA(pGl, splat2(pR3), w2v[3]);
      w2v[4] = PKFMA(pGl, splat2(pR4), w2v[4]);
      w2v[5] = PKFMA(pGl, splat2(pR5), w2v[5]);
      w2v[6] = PKFMA(pGl, splat2(pR6), w2v[6]);
      w2v[7] = PKFMA(pGl, splat2(pR7), w2v[7]);
      b2v += pGl;
    };

    BAR();  // init: B wrote buffer 0

    auto EPA = [&](int e) {
      const int ep = e & 1;
      const int tpo = ep * 16, kko = 32 + ep * 5, dao = 48 + ep * 16;
      // v prefetch for epoch e+2 (stays in flight across the barrier)
      int rv0 = 4 * e + 9;  if (rv0 > 4095) rv0 = 4095;
      int rv1 = 4 * e + 11; if (rv1 > 4095) rv1 = 4095;
      f32x2 vI0 = *(const f32x2*)(hb + (size_t)rv0 * HIDDIM + d0);
      f32x2 vI1 = *(const f32x2*)(hb + (size_t)rv1 * HIDDIM + d0);
      float tpPA = sm[tpo + sig], tpPB = sm[tpo + 4 + sig];
      float tpQA = sm[tpo + 8 + sig], tpQB = sm[tpo + 12 + sig];
      float kk1 = sm[kko], kk2 = sm[kko + 1], kk3 = sm[kko + 2],
            kk4 = sm[kko + 3], kk5 = sm[kko + 4];
      APPLY_PEND();  // prev epoch's deferred W2/b2; shadows the LDS reads
      float aA = fmaf(dm2A, kk1, fmaf(dm1A, kk2, tpPA + b1A));
      float aB = fmaf(dm2B, kk1, fmaf(dm1B, kk2, tpPB + b1B));
      float daPA, daPB;
      CORE(aA, aB, vS[0], daPA, daPB, false);
      if (rowlead) { sm[dao + sig] = daPA; sm[dao + 4 + sig] = daPB; }
      b1A += daPA;
      b1B += daPB;
      float aQA = fmaf(dm2A, kk3, fmaf(dm1A, kk4, fmaf(daPA, kk5, tpQA + b1A)));
      float aQB = fmaf(dm2B, kk3, fmaf(dm1B, kk4, fmaf(daPB, kk5, tpQB + b1B)));
      float daQA, daQB;
      CORE(aQA, aQB, vS[1], daQA, daQB, true);
      if (rowlead) { sm[dao + 8 + sig] = daQA; sm[dao + 12 + sig] = daQB; }
      b1A += daQA;
      b1B += daQB;
      dm2A = daPA; dm2B = daPB;
      dm1A = daQA; dm1B = daQB;
      vS[0] = vS[2]; vS[1] = vS[3]; vS[2] = vI0; vS[3] = vI1;
      BAR();
    };

    for (int e = 0; e < 1023; ++e) EPA(e);
    // ---- tail epoch 1023 (buffer 1): step 2046 + final predict ----
    {
      float tpPA = sm[16 + sig], tpPB = sm[20 + sig];
      float tpQA = sm[24 + sig], tpQB = sm[28 + sig];
      float kk1 = sm[37], kk2 = sm[38], kk3 = sm[39], kk4 = sm[40],
            kk5 = sm[41];
      APPLY_PEND();
      float aA = fmaf(dm2A, kk1, fmaf(dm1A, kk2, tpPA + b1A));
      float aB = fmaf(dm2B, kk1, fmaf(dm1B, kk2, tpPB + b1B));
      float daA, daB;
      CORE(aA, aB, vS[0], daA, daB, false);  // step 2046
      b1A += daA;
      b1B += daB;
      // a(2047) = W1_fin·x + b1_fin  (x fed through as k(2047))
      float fA = fmaf(dm2A, kk3, fmaf(dm1A, kk4, fmaf(daA, kk5, tpQA + b1A)));
      float fB = fmaf(dm2B, kk3, fmaf(dm1B, kk4, fmaf(daB, kk5, tpQB + b1B)));
      float rA = fmaxf(fA, 0.0f), rB = fmaxf(fB, 0.0f);
      float r0 = RL(rA, 0), r1 = RL(rA, 32), r2 = RL(rA, 16), r3 = RL(rA, 48);
      float r4 = RL(rB, 0), r5 = RL(rB, 32), r6 = RL(rB, 16), r7 = RL(rB, 48);
      f32x2 o = PKFMA(w2v[0], splat2(r0), b2v);
      o = PKFMA(w2v[1], splat2(r1), o);
      o = PKFMA(w2v[2], splat2(r2), o);
      o = PKFMA(w2v[3], splat2(r3), o);
      o = PKFMA(w2v[4], splat2(r4), o);
      o = PKFMA(w2v[5], splat2(r5), o);
      o = PKFMA(w2v[6], splat2(r6), o);
      o = PKFMA(w2v[7], splat2(r7), o);
      *(f32x2*)(out + (size_t)b * HIDDIM + d0) = o;
    }
  } else {
    // ======================= WAVE B (W1 owner) =======================
    f32x2 w1v[8];
#pragma unroll
    for (int i = 0; i < 8; ++i)
      w1v[i] = *(const f32x2*)(W1 + i * HIDDIM + d0);
    // k(m) = row 2m (m<2047); k(2047) := x = row 4095
    f32x2 kR2 = *(const f32x2*)(hb + 0 * HIDDIM + d0);   // k(0)
    f32x2 kR3 = *(const f32x2*)(hb + 2 * HIDDIM + d0);   // k(1)
    f32x2 kR4 = *(const f32x2*)(hb + 4 * HIDDIM + d0);   // k(2)
    f32x2 kR5 = *(const f32x2*)(hb + 6 * HIDDIM + d0);   // k(3)
    f32x2 kR0 = kR2, kR1 = kR2;                          // dummies (da=0)
    f32x2 kI0 = *(const f32x2*)(hb + 8 * HIDDIM + d0);   // k(4)
    f32x2 kI1 = *(const f32x2*)(hb + 10 * HIDDIM + d0);  // k(5)
    // zero da slots (read by B at f=0 before A wrote anything)
    if (lane < 16) sm[64 + lane] = 0.0f;
    // init buffer 0: a(0) base, TP(1), kk
    {
      float pa[8], pb[8];
#pragma unroll
      for (int i = 0; i < 8; ++i) {
        pa[i] = dot2(w1v[i], kR2);
        pb[i] = dot2(w1v[i], kR3);
      }
      float zA = allred4(pa[0], pa[1], pa[2], pa[3]);
      float zB = allred4(pa[4], pa[5], pa[6], pa[7]);
      float tA = allred4(pb[0], pb[1], pb[2], pb[3]);
      float tB = allred4(pb[4], pb[5], pb[6], pb[7]);
      float kk01 = allred1(dot2(kR2, kR3));
      if (rowlead) {
        sm[0 + sig] = zA;   sm[4 + sig] = zB;
        sm[8 + sig] = tA;   sm[12 + sig] = tB;
      }
      if (lane < 4) sm[32 + lane] = 0.0f;  // kk1..kk4 = 0 (da=0 at epoch 0)
      if (lane == 0) sm[36] = kk01;        // kk5 = k(0)·k(1)
    }
    BAR();  // init

    auto EPB = [&](int f) {
      const int ep = f & 1;
      const int dao = 48 + (1 - ep) * 16;
      const int tpo = (1 - ep) * 16, kko = 32 + (1 - ep) * 5;
      int m6 = 2 * f + 6, m7 = 2 * f + 7;
      int r6 = (m6 >= 2047) ? 4095 : 2 * m6;
      int r7 = (m7 >= 2047) ? 4095 : 2 * m7;
      f32x2 kN0 = *(const f32x2*)(hb + (size_t)r6 * HIDDIM + d0);
      f32x2 kN1 = *(const f32x2*)(hb + (size_t)r7 * HIDDIM + d0);
      float4 q0 = *(float4*)&sm[dao], q1 = *(float4*)&sm[dao + 4];
      float4 q2 = *(float4*)&sm[dao + 8], q3 = *(float4*)&sm[dao + 12];
      // kk partials (k-only) fill the DA-read shadow
      float c1 = dot2(kR2, kR4), c2 = dot2(kR3, kR4);
      float c3 = dot2(kR2, kR5), c4 = dot2(kR3, kR5);
      float c5 = dot2(kR4, kR5);
      float ykk = allred4(c1, c2, c3, c4);
      float yk5 = allred1(c5);
      if (rowlead) sm[kko + sig] = ykk;
      if (lane == 0) sm[kko + 4] = yk5;
      float dP[8] = {q0.x, q0.y, q0.z, q0.w, q1.x, q1.y, q1.z, q1.w};
      float dQ[8] = {q2.x, q2.y, q2.z, q2.w, q3.x, q3.y, q3.z, q3.w};
      // two rank-1 W1 updates (packed)
#pragma unroll
      for (int i = 0; i < 8; ++i) {
        w1v[i] = PKFMA(splat2(dP[i]), kR0, w1v[i]);
        w1v[i] = PKFMA(splat2(dQ[i]), kR1, w1v[i]);
      }
      float tp[8];
#pragma unroll
      for (int i = 0; i < 8; ++i) tp[i] = dot2(w1v[i], kR4);
      float tA = allred4(tp[0], tp[1], tp[2], tp[3]);
      float tB = allred4(tp[4], tp[5], tp[6], tp[7]);
#pragma unroll
      for (int i = 0; i < 8; ++i) tp[i] = dot2(w1v[i], kR5);
      float uA = allred4(tp[0], tp[1], tp[2], tp[3]);
      float uB = allred4(tp[4], tp[5], tp[6], tp[7]);
      if (rowlead) {
        sm[tpo + sig] = tA;      sm[tpo + 4 + sig] = tB;
        sm[tpo + 8 + sig] = uA;  sm[tpo + 12 + sig] = uB;
      }
      kR0 = kR2; kR1 = kR3; kR2 = kR4; kR3 = kR5;
      kR4 = kI0; kR5 = kI1; kI0 = kN0; kI1 = kN1;
      BAR();
    };

    for (int f = 0; f < 1023; ++f) EPB(f);
    EPB(1023);  // pad epoch: A's tail consumes buffer 1 data already written;
                // this EPB writes buffer 0 (unused) and matches A's last BAR
  }
}

extern "C" void kernel_launch(void* const* d_in, const int* in_sizes, int n_in,
                              void* d_out, int out_size, void* d_ws, size_t ws_size,
                              hipStream_t stream) {
  const float* h  = (const float*)d_in[0];
  const float* W1 = (const float*)d_in[1];
  const float* b1 = (const float*)d_in[2];
  const float* W2 = (const float*)d_in[3];
  const float* b2 = (const float*)d_in[4];
  float* out = (float*)d_out;
  ttt_kernel<<<256, 128, 0, stream>>>(h, W1, b1, W2, b2, out);
}

// Round 20
// 518.054 us; speedup vs baseline: 1.9722x; 1.1691x over previous
//
#include <hip/hip_runtime.h>

#define LRC 0.01f
#define LSEQ 4096
#define HIDDIM 128

typedef float f32x2 __attribute__((ext_vector_type(2)));
typedef unsigned int u32x2 __attribute__((ext_vector_type(2)));

#define RL(x, L) __int_as_float(__builtin_amdgcn_readlane(__float_as_int(x), (L)))
#define RORADD(x, ctrl)                                                      \
  x += __int_as_float(__builtin_amdgcn_update_dpp(                           \
      0, __float_as_int(x), (ctrl), 0xf, 0xf, true))

// (validated R5..R13) 4 concurrent 64-lane sums, row-mapped outputs:
// row g holds sum of x_{sig(g)}, sig = [0,2,1,3]. Rowlead write at
// sm[base+sig] lands value c at sm[base+c].
__device__ __forceinline__ float allred4(float x0, float x1, float x2,
                                         float x3) {
  u32x2 s1 = __builtin_amdgcn_permlane32_swap(__float_as_uint(x0),
                                              __float_as_uint(x1), false, false);
  float z01 = __uint_as_float(s1.x) + __uint_as_float(s1.y);
  u32x2 s2 = __builtin_amdgcn_permlane32_swap(__float_as_uint(x2),
                                              __float_as_uint(x3), false, false);
  float z23 = __uint_as_float(s2.x) + __uint_as_float(s2.y);
  u32x2 s3 = __builtin_amdgcn_permlane16_swap(__float_as_uint(z01),
                                              __float_as_uint(z23), false, false);
  float y = __uint_as_float(s3.x) + __uint_as_float(s3.y);
  RORADD(y, 0x128); RORADD(y, 0x124); RORADD(y, 0x122); RORADD(y, 0x121);
  return y;
}

// (validated R6) 64-lane sum, all-lane-uniform result.
__device__ __forceinline__ float allred1(float x) {
  u32x2 s1 = __builtin_amdgcn_permlane32_swap(__float_as_uint(x),
                                              __float_as_uint(x), false, false);
  float z = __uint_as_float(s1.x) + __uint_as_float(s1.y);
  u32x2 s2 = __builtin_amdgcn_permlane16_swap(__float_as_uint(z),
                                              __float_as_uint(z), false, false);
  z = __uint_as_float(s2.x) + __uint_as_float(s2.y);
  RORADD(z, 0x128); RORADD(z, 0x124); RORADD(z, 0x122); RORADD(z, 0x121);
  return z;
}

__device__ __forceinline__ float dot2(f32x2 a, f32x2 b) {
  return fmaf(a.x, b.x, a.y * b.y);
}

// E=2 epochs (R13 structure, validated 533us) with hardened sync:
// __syncthreads() (full fence) instead of the hand-rolled lgkmcnt barrier.
// LDS floats: TP[ep][2][8] at ep*16 | KK[ep][5] at 32+ep*5 | DA[ep][2][8]
// at 48+ep*16.
// A@e: reads TP/KK[e&1] (B wrote in e-1), writes DA[e&1].
// B@f: reads DA[(f-1)&1] (A wrote in f-1), writes TP/KK[(f+1)&1].
// One barrier per epoch (2 steps).
// Factorization: a(P=2e) = TPb(P) + da(2e-2)kk1 + da(2e-1)kk2 + b1, with
// TPb(P) = red(W[2e-3] k(P)); a(Q=2e+1) adds da(P)kk5. B's kk set (epoch
// e-1, k-window k(2e-2..2e+1)): kk1=k(2e-2)k(2e), kk2=k(2e-1)k(2e),
// kk3=k(2e-2)k(2e+1), kk4=k(2e-1)k(2e+1), kk5=k(2e)k(2e+1).
__global__ __launch_bounds__(128) void ttt_kernel(
    const float* __restrict__ h, const float* __restrict__ W1,
    const float* __restrict__ b1, const float* __restrict__ W2,
    const float* __restrict__ b2, float* __restrict__ out) {
  __shared__ __align__(16) float sm[80];
  const int b = blockIdx.x;
  const int tid = threadIdx.x;
  const int wv = tid >> 6;
  const int lane = tid & 63;
  const int g = lane >> 4;
  const int sig = ((g & 1) << 1) | (g >> 1);
  const int d0 = lane * 2;
  const bool rowlead = ((lane & 15) == 0);
  const float* __restrict__ hb = h + (size_t)b * (LSEQ * HIDDIM);

  if (wv == 0) {
    // ======================= WAVE A (serial core) =======================
    const float cneg = -(LRC * 2.0f / (float)HIDDIM);
    f32x2 w2v[8];
#pragma unroll
    for (int i = 0; i < 8; ++i) {
      w2v[i].x = W2[(size_t)d0 * 8 + i];
      w2v[i].y = W2[(size_t)(d0 + 1) * 8 + i];
    }
    f32x2 b2v = *(const f32x2*)(b2 + d0);
    float b1A = b1[sig], b1B = b1[4 + sig];
    // v(j) = row 2j+1; 4 live slots (2 epochs)
    f32x2 vS[4];
#pragma unroll
    for (int x = 0; x < 4; ++x)
      vS[x] = *(const f32x2*)(hb + (size_t)(2 * x + 1) * HIDDIM + d0);
    float pGlx = 0.0f, pGly = 0.0f;  // deferred Q-step W2/b2 update
    float pR0 = 0, pR1 = 0, pR2 = 0, pR3 = 0, pR4 = 0, pR5 = 0, pR6 = 0,
          pR7 = 0;
    float dm2A = 0, dm2B = 0, dm1A = 0, dm1B = 0;  // da(j-2), da(j-1)

    auto CORE = [&](float aA, float aB, f32x2 vcur, float& daAo, float& daBo,
                    bool defer) {
      float rA = fmaxf(aA, 0.0f), rB = fmaxf(aB, 0.0f);
      float r0 = RL(rA, 0), r1 = RL(rA, 32), r2 = RL(rA, 16), r3 = RL(rA, 48);
      float r4 = RL(rB, 0), r5 = RL(rB, 32), r6 = RL(rB, 16), r7 = RL(rB, 48);
      float px0 = fmaf(w2v[0].x, r0, b2v.x), py0 = fmaf(w2v[0].y, r0, b2v.y);
      float px1 = w2v[1].x * r1, py1 = w2v[1].y * r1;
      px0 = fmaf(w2v[2].x, r2, px0); py0 = fmaf(w2v[2].y, r2, py0);
      px1 = fmaf(w2v[3].x, r3, px1); py1 = fmaf(w2v[3].y, r3, py1);
      px0 = fmaf(w2v[4].x, r4, px0); py0 = fmaf(w2v[4].y, r4, py0);
      px1 = fmaf(w2v[5].x, r5, px1); py1 = fmaf(w2v[5].y, r5, py1);
      px0 = fmaf(w2v[6].x, r6, px0); py0 = fmaf(w2v[6].y, r6, py0);
      px1 = fmaf(w2v[7].x, r7, px1); py1 = fmaf(w2v[7].y, r7, py1);
      float glx = (px0 + px1 - vcur.x) * cneg;
      float gly = (py0 + py1 - vcur.y) * cneg;
      float dp[8];
#pragma unroll
      for (int i = 0; i < 8; ++i) dp[i] = fmaf(w2v[i].x, glx, w2v[i].y * gly);
      float zA = allred4(dp[0], dp[1], dp[2], dp[3]);
      float zB = allred4(dp[4], dp[5], dp[6], dp[7]);
      daAo = (aA > 0.0f) ? zA : 0.0f;  // == -lr * da_ref
      daBo = (aB > 0.0f) ? zB : 0.0f;
      if (!defer) {
        w2v[0].x = fmaf(glx, r0, w2v[0].x); w2v[0].y = fmaf(gly, r0, w2v[0].y);
        w2v[1].x = fmaf(glx, r1, w2v[1].x); w2v[1].y = fmaf(gly, r1, w2v[1].y);
        w2v[2].x = fmaf(glx, r2, w2v[2].x); w2v[2].y = fmaf(gly, r2, w2v[2].y);
        w2v[3].x = fmaf(glx, r3, w2v[3].x); w2v[3].y = fmaf(gly, r3, w2v[3].y);
        w2v[4].x = fmaf(glx, r4, w2v[4].x); w2v[4].y = fmaf(gly, r4, w2v[4].y);
        w2v[5].x = fmaf(glx, r5, w2v[5].x); w2v[5].y = fmaf(gly, r5, w2v[5].y);
        w2v[6].x = fmaf(glx, r6, w2v[6].x); w2v[6].y = fmaf(gly, r6, w2v[6].y);
        w2v[7].x = fmaf(glx, r7, w2v[7].x); w2v[7].y = fmaf(gly, r7, w2v[7].y);
        b2v.x += glx;
        b2v.y += gly;
      } else {
        pGlx = glx; pGly = gly;
        pR0 = r0; pR1 = r1; pR2 = r2; pR3 = r3;
        pR4 = r4; pR5 = r5; pR6 = r6; pR7 = r7;
      }
    };
    auto APPLY_PEND = [&]() {
      w2v[0].x = fmaf(pGlx, pR0, w2v[0].x); w2v[0].y = fmaf(pGly, pR0, w2v[0].y);
      w2v[1].x = fmaf(pGlx, pR1, w2v[1].x); w2v[1].y = fmaf(pGly, pR1, w2v[1].y);
      w2v[2].x = fmaf(pGlx, pR2, w2v[2].x); w2v[2].y = fmaf(pGly, pR2, w2v[2].y);
      w2v[3].x = fmaf(pGlx, pR3, w2v[3].x); w2v[3].y = fmaf(pGly, pR3, w2v[3].y);
      w2v[4].x = fmaf(pGlx, pR4, w2v[4].x); w2v[4].y = fmaf(pGly, pR4, w2v[4].y);
      w2v[5].x = fmaf(pGlx, pR5, w2v[5].x); w2v[5].y = fmaf(pGly, pR5, w2v[5].y);
      w2v[6].x = fmaf(pGlx, pR6, w2v[6].x); w2v[6].y = fmaf(pGly, pR6, w2v[6].y);
      w2v[7].x = fmaf(pGlx, pR7, w2v[7].x); w2v[7].y = fmaf(pGly, pR7, w2v[7].y);
      b2v.x += pGlx;
      b2v.y += pGly;
    };

    auto EPA = [&](int ep, int e) {
      const int tpo = ep * 16, kko = 32 + ep * 5, dao = 48 + ep * 16;
      int rv0 = 4 * e + 9;  if (rv0 > 4095) rv0 = 4095;
      int rv1 = 4 * e + 11; if (rv1 > 4095) rv1 = 4095;
      f32x2 vI0 = *(const f32x2*)(hb + (size_t)rv0 * HIDDIM + d0);
      f32x2 vI1 = *(const f32x2*)(hb + (size_t)rv1 * HIDDIM + d0);
      float tpPA = sm[tpo + sig], tpPB = sm[tpo + 4 + sig];
      float tpQA = sm[tpo + 8 + sig], tpQB = sm[tpo + 12 + sig];
      float kk1 = sm[kko], kk2 = sm[kko + 1], kk3 = sm[kko + 2],
            kk4 = sm[kko + 3], kk5 = sm[kko + 4];
      APPLY_PEND();  // prev epoch's Q update; shadows the LDS reads
      float aA = fmaf(dm2A, kk1, fmaf(dm1A, kk2, tpPA + b1A));
      float aB = fmaf(dm2B, kk1, fmaf(dm1B, kk2, tpPB + b1B));
      float daPA, daPB;
      CORE(aA, aB, vS[0], daPA, daPB, false);
      if (rowlead) { sm[dao + sig] = daPA; sm[dao + 4 + sig] = daPB; }
      b1A += daPA;
      b1B += daPB;
      float aQA = fmaf(dm2A, kk3, fmaf(dm1A, kk4, fmaf(daPA, kk5, tpQA + b1A)));
      float aQB = fmaf(dm2B, kk3, fmaf(dm1B, kk4, fmaf(daPB, kk5, tpQB + b1B)));
      float daQA, daQB;
      CORE(aQA, aQB, vS[1], daQA, daQB, true);
      if (rowlead) { sm[dao + 8 + sig] = daQA; sm[dao + 12 + sig] = daQB; }
      b1A += daQA;
      b1B += daQB;
      dm2A = daPA; dm2B = daPB;
      dm1A = daQA; dm1B = daQB;
      vS[0] = vS[2]; vS[1] = vS[3]; vS[2] = vI0; vS[3] = vI1;
      __syncthreads();
    };

    __syncthreads();  // init: B wrote buffer 0

    for (int pr = 0; pr < 511; ++pr) {
      EPA(0, 2 * pr);
      EPA(1, 2 * pr + 1);
    }
    EPA(0, 1022);
    // tail: epoch 1023 = step 2046 + final predict (buffer ep=1)
    {
      float tpPA = sm[16 + sig], tpPB = sm[20 + sig];
      float tpQA = sm[24 + sig], tpQB = sm[28 + sig];
      float kk1 = sm[37], kk2 = sm[38], kk3 = sm[39], kk4 = sm[40],
            kk5 = sm[41];
      APPLY_PEND();
      float aA = fmaf(dm2A, kk1, fmaf(dm1A, kk2, tpPA + b1A));
      float aB = fmaf(dm2B, kk1, fmaf(dm1B, kk2, tpPB + b1B));
      float daA, daB;
      CORE(aA, aB, vS[0], daA, daB, false);  // step 2046, W2/b2 inline
      b1A += daA;
      b1B += daB;
      // a(2047) = red(W[2046] x) + b1  (x = row 4095, fed in as k(2047))
      float fA = fmaf(dm2A, kk3, fmaf(dm1A, kk4, fmaf(daA, kk5, tpQA + b1A)));
      float fB = fmaf(dm2B, kk3, fmaf(dm1B, kk4, fmaf(daB, kk5, tpQB + b1B)));
      float rA = fmaxf(fA, 0.0f), rB = fmaxf(fB, 0.0f);
      float r0 = RL(rA, 0), r1 = RL(rA, 32), r2 = RL(rA, 16), r3 = RL(rA, 48);
      float r4 = RL(rB, 0), r5 = RL(rB, 32), r6 = RL(rB, 16), r7 = RL(rB, 48);
      float ox = fmaf(w2v[0].x, r0, b2v.x), oy = fmaf(w2v[0].y, r0, b2v.y);
      ox = fmaf(w2v[1].x, r1, ox); oy = fmaf(w2v[1].y, r1, oy);
      ox = fmaf(w2v[2].x, r2, ox); oy = fmaf(w2v[2].y, r2, oy);
      ox = fmaf(w2v[3].x, r3, ox); oy = fmaf(w2v[3].y, r3, oy);
      ox = fmaf(w2v[4].x, r4, ox); oy = fmaf(w2v[4].y, r4, oy);
      ox = fmaf(w2v[5].x, r5, ox); oy = fmaf(w2v[5].y, r5, oy);
      ox = fmaf(w2v[6].x, r6, ox); oy = fmaf(w2v[6].y, r6, oy);
      ox = fmaf(w2v[7].x, r7, ox); oy = fmaf(w2v[7].y, r7, oy);
      f32x2 o = {ox, oy};
      *(f32x2*)(out + (size_t)b * HIDDIM + d0) = o;
    }
  } else {
    // ======================= WAVE B (W1 owner) =======================
    f32x2 w1v[8];
#pragma unroll
    for (int i = 0; i < 8; ++i)
      w1v[i] = *(const f32x2*)(W1 + i * HIDDIM + d0);
    // k(m) = row 2m (m<2047); k(2047) := x = row 4095
    f32x2 kR2 = *(const f32x2*)(hb + 0 * HIDDIM + d0);   // k(0)
    f32x2 kR3 = *(const f32x2*)(hb + 2 * HIDDIM + d0);   // k(1)
    f32x2 kR4 = *(const f32x2*)(hb + 4 * HIDDIM + d0);   // k(2)
    f32x2 kR5 = *(const f32x2*)(hb + 6 * HIDDIM + d0);   // k(3)
    f32x2 kR0 = kR2, kR1 = kR2;                          // dummies (da=0)
    f32x2 kI0 = *(const f32x2*)(hb + 8 * HIDDIM + d0);   // k(4)
    f32x2 kI1 = *(const f32x2*)(hb + 10 * HIDDIM + d0);  // k(5)
    if (lane < 16) sm[64 + lane] = 0.0f;  // zero DA[1] (read at epoch 0)
    {
      float pa[8], pb[8];
#pragma unroll
      for (int i = 0; i < 8; ++i) {
        pa[i] = dot2(w1v[i], kR2);
        pb[i] = dot2(w1v[i], kR3);
      }
      float zA = allred4(pa[0], pa[1], pa[2], pa[3]);
      float zB = allred4(pa[4], pa[5], pa[6], pa[7]);
      float tA = allred4(pb[0], pb[1], pb[2], pb[3]);
      float tB = allred4(pb[4], pb[5], pb[6], pb[7]);
      float kk01 = allred1(dot2(kR2, kR3));
      if (rowlead) {
        sm[0 + sig] = zA;   sm[4 + sig] = zB;    // a(0) base
        sm[8 + sig] = tA;   sm[12 + sig] = tB;   // TP(1)
      }
      if (lane < 4) sm[32 + lane] = 0.0f;        // kk1..kk4 = 0 (da=0)
      if (lane == 0) sm[36] = kk01;              // kk5 = k(0)·k(1)
    }
    __syncthreads();  // init

    auto EPB = [&](int ep, int e) {
      const int dao = 48 + (1 - ep) * 16;
      const int tpo = (1 - ep) * 16, kko = 32 + (1 - ep) * 5;
      int m6 = 2 * e + 6, m7 = 2 * e + 7;
      int r6 = (m6 >= 2047) ? 4095 : 2 * m6;
      int r7 = (m7 >= 2047) ? 4095 : 2 * m7;
      f32x2 kN0 = *(const f32x2*)(hb + (size_t)r6 * HIDDIM + d0);
      f32x2 kN1 = *(const f32x2*)(hb + (size_t)r7 * HIDDIM + d0);
      float4 qa = *(float4*)&sm[dao], qb = *(float4*)&sm[dao + 4];
      float4 qc = *(float4*)&sm[dao + 8], qd = *(float4*)&sm[dao + 12];
      // kk partials (k-only) fill the da-read shadow
      float c1 = dot2(kR2, kR4), c2 = dot2(kR3, kR4);
      float c3 = dot2(kR2, kR5), c4 = dot2(kR3, kR5);
      float c5 = dot2(kR4, kR5);
      float ykk = allred4(c1, c2, c3, c4);
      float yk5 = allred1(c5);
      float dP[8] = {qa.x, qa.y, qa.z, qa.w, qb.x, qb.y, qb.z, qb.w};
      float dQ[8] = {qc.x, qc.y, qc.z, qc.w, qd.x, qd.y, qd.z, qd.w};
#pragma unroll
      for (int i = 0; i < 8; ++i) {
        w1v[i].x = fmaf(dP[i], kR0.x, w1v[i].x);
        w1v[i].y = fmaf(dP[i], kR0.y, w1v[i].y);
        w1v[i].x = fmaf(dQ[i], kR1.x, w1v[i].x);
        w1v[i].y = fmaf(dQ[i], kR1.y, w1v[i].y);
      }
      float tp[8];
#pragma unroll
      for (int i = 0; i < 8; ++i) tp[i] = dot2(w1v[i], kR4);
      float tA = allred4(tp[0], tp[1], tp[2], tp[3]);
      float tB = allred4(tp[4], tp[5], tp[6], tp[7]);
#pragma unroll
      for (int i = 0; i < 8; ++i) tp[i] = dot2(w1v[i], kR5);
      float uA = allred4(tp[0], tp[1], tp[2], tp[3]);
      float uB = allred4(tp[4], tp[5], tp[6], tp[7]);
      if (rowlead) {
        sm[tpo + sig] = tA;      sm[tpo + 4 + sig] = tB;
        sm[tpo + 8 + sig] = uA;  sm[tpo + 12 + sig] = uB;
        sm[kko + sig] = ykk;
      }
      if (lane == 0) sm[kko + 4] = yk5;
      kR0 = kR2; kR1 = kR3; kR2 = kR4; kR3 = kR5;
      kR4 = kI0; kR5 = kI1; kI0 = kN0; kI1 = kN1;
      __syncthreads();
    };

    for (int pr = 0; pr < 511; ++pr) {
      EPB(0, 2 * pr);
      EPB(1, 2 * pr + 1);
    }
    EPB(0, 1022);
  }
}

extern "C" void kernel_launch(void* const* d_in, const int* in_sizes, int n_in,
                              void* d_out, int out_size, void* d_ws, size_t ws_size,
                              hipStream_t stream) {
  const float* h  = (const float*)d_in[0];
  const float* W1 = (const float*)d_in[1];
  const float* b1 = (const float*)d_in[2];
  const float* W2 = (const float*)d_in[3];
  const float* b2 = (const float*)d_in[4];
  float* out = (float*)d_out;
  ttt_kernel<<<256, 128, 0, stream>>>(h, W1, b1, W2, b2, out);
}